// Round 1
// baseline (9754.179 us; speedup 1.0000x reference)
//
#include <hip/hip_runtime.h>
#include <math.h>

#define N_NODES 30000
#define N_EDGES 480000
#define DEGN 0.25f   // 1/sqrt(16)

__device__ __forceinline__ float fsilu(float x){ return x / (1.f + __expf(-x)); }
__device__ __forceinline__ float fsig (float x){ return 1.f / (1.f + __expf(-x)); }

// ---- per-edge geometry + edge_attr (once) ----
__global__ __launch_bounds__(256) void prep_edges(
    const float* __restrict__ pos, const int* __restrict__ ei,
    const int* __restrict__ bond_mask, const float* __restrict__ bond_emb,
    float* __restrict__ ea, float* __restrict__ y1)
{
  int e = blockIdx.x*256 + threadIdx.x;
  if (e >= N_EDGES) return;
  int src = ei[e], dst = ei[N_EDGES + e];
  float ax = pos[src*3+0], ay = pos[src*3+1], az = pos[src*3+2];
  float bx = pos[dst*3+0], by = pos[dst*3+1], bz = pos[dst*3+2];
  float vx = ax-bx, vy = ay-by, vz = az-bz;
  float r = sqrtf(vx*vx + vy*vy + vz*vz);
  float inv = 1.f / fmaxf(r, 1e-9f);
  const float s3 = 1.7320508075688772f;
  y1[e*3+0] = s3*vx*inv; y1[e*3+1] = s3*vy*inv; y1[e*3+2] = s3*vz*inv;
  int bm = bond_mask[e];
  float eav[16];
  #pragma unroll
  for (int q=0;q<8;q++) eav[q] = bond_emb[bm*8+q];
  const float step = 5.0f/9.0f;
  #pragma unroll
  for (int j=0;j<8;j++){
    float vj = (float)(j+1)*step;
    float d = (r - vj)/step;
    eav[8+j] = __expf(-d*d) * (1.0f/1.12f);
  }
  float4* o = (float4*)(ea + (size_t)e*16);
  o[0] = make_float4(eav[0],eav[1],eav[2],eav[3]);
  o[1] = make_float4(eav[4],eav[5],eav[6],eav[7]);
  o[2] = make_float4(eav[8],eav[9],eav[10],eav[11]);
  o[3] = make_float4(eav[12],eav[13],eav[14],eav[15]);
}

// ---- s = atom_emb[atom_type] @ w_init ----
__global__ __launch_bounds__(256) void init_nodes(
    const int* __restrict__ atom_type, const float* __restrict__ atom_emb,
    const float* __restrict__ w_init, float* __restrict__ s)
{
  int n = blockIdx.x*256 + threadIdx.x;
  if (n >= N_NODES) return;
  int t = atom_type[n];
  float acc[64];
  #pragma unroll
  for (int o=0;o<64;o++) acc[o]=0.f;
  for (int k=0;k<64;k++){
    float ek = atom_emb[t*64+k];
    #pragma unroll
    for (int o=0;o<64;o++) acc[o] = fmaf(ek, w_init[k*64+o], acc[o]);
  }
  float4* so = (float4*)(s + (size_t)n*64);
  #pragma unroll
  for (int q=0;q<16;q++) so[q] = make_float4(acc[4*q],acc[4*q+1],acc[4*q+2],acc[4*q+3]);
}

// ---- W2 [3][64][176] -> W2T [3][176][64] so dots read contiguous rows ----
__global__ void transpose_w2(const float* __restrict__ w2, float* __restrict__ w2t)
{
  int i = blockIdx.x*256 + threadIdx.x;
  if (i >= 3*64*176) return;
  int l = i / (64*176); int rem = i - l*(64*176);
  int k = rem / 176, c = rem - k*176;
  w2t[l*176*64 + c*64 + k] = w2[i];
}

// ---- fused edge kernel: MLP -> TP messages (lin_v folded) -> atomic scatter ----
__global__ __launch_bounds__(256) void edge_msg(
    const float* __restrict__ ea, const float* __restrict__ y1v,
    const int* __restrict__ ei,
    const float* __restrict__ s, const float* __restrict__ v,
    const float* __restrict__ W1,    // [16][64]
    const float* __restrict__ b1,    // [64]
    const float* __restrict__ W2T,   // [176][64]
    const float* __restrict__ linv,  // [96][16]
    float* __restrict__ agg_s,       // [N][80]
    float* __restrict__ agg_v)       // [N][16][3]  (== out_v contribution)
{
  int e = blockIdx.x*256 + threadIdx.x;
  if (e >= N_EDGES) return;
  int src = ei[e], dst = ei[N_EDGES + e];

  // h = silu(ea @ W1 + b1)
  float h[64];
  {
    float eav[16];
    const float4* eap = (const float4*)(ea + (size_t)e*16);
    #pragma unroll
    for (int q=0;q<4;q++){ float4 t4 = eap[q]; eav[4*q]=t4.x; eav[4*q+1]=t4.y; eav[4*q+2]=t4.z; eav[4*q+3]=t4.w; }
    #pragma unroll
    for (int k=0;k<64;k++) h[k] = b1[k];
    #pragma unroll
    for (int j=0;j<16;j++){
      float a = eav[j];
      #pragma unroll
      for (int k=0;k<64;k++) h[k] = fmaf(a, W1[j*64+k], h[k]);
    }
    #pragma unroll
    for (int k=0;k<64;k++) h[k] = fsilu(h[k]);
  }

  float yx = y1v[e*3+0], yy = y1v[e*3+1], yz = y1v[e*3+2];

  // phase B: scalar channels (w_ss*se) and a_o = sum_i w_sv_i*se_i*lin_v[i][o]
  float a_o[16];
  #pragma unroll
  for (int o=0;o<16;o++) a_o[o]=0.f;

  for (int i0=0;i0<64;i0+=4){
    float4 se4 = *(const float4*)(s + (size_t)src*64 + i0);
    float se[4] = {se4.x, se4.y, se4.z, se4.w};
    float wss[4] = {0,0,0,0}, wsv[4] = {0,0,0,0};
    #pragma unroll
    for (int k=0;k<64;k++){
      float hk = h[k];
      #pragma unroll
      for (int q=0;q<4;q++){
        wss[q] = fmaf(hk, W2T[(i0+q)*64+k], wss[q]);
        wsv[q] = fmaf(hk, W2T[(80+i0+q)*64+k], wsv[q]);
      }
    }
    #pragma unroll
    for (int q=0;q<4;q++){
      int i = i0+q;
      atomicAdd(agg_s + (size_t)dst*80 + i, DEGN*wss[q]*se[q]);
      float t = wsv[q]*se[q];
      #pragma unroll
      for (int o=0;o<16;o++) a_o[o] = fmaf(t, linv[i*16+o], a_o[o]);
    }
  }

  // phase C: vector channels; acc[o][c] accumulates (m_v @ lin_v)
  float acc[16][3];
  #pragma unroll
  for (int o=0;o<16;o++){ acc[o][0]=a_o[o]*yx; acc[o][1]=a_o[o]*yy; acc[o][2]=a_o[o]*yz; }

  for (int j=0;j<16;j++){
    float wx = v[(size_t)src*48 + j*3 + 0];
    float wy = v[(size_t)src*48 + j*3 + 1];
    float wz = v[(size_t)src*48 + j*3 + 2];
    float wvs=0.f, wvv=0.f, wcx=0.f;
    #pragma unroll
    for (int k=0;k<64;k++){
      float hk = h[k];
      wvs = fmaf(hk, W2T[( 64+j)*64+k], wvs);
      wvv = fmaf(hk, W2T[(144+j)*64+k], wvv);
      wcx = fmaf(hk, W2T[(160+j)*64+k], wcx);
    }
    float dvy = wx*yx + wy*yy + wz*yz;
    atomicAdd(agg_s + (size_t)dst*80 + 64 + j, DEGN*wvs*dvy);
    float cx = wy*yz - wz*yy;
    float cy = wz*yx - wx*yz;
    float cz = wx*yy - wy*yx;
    #pragma unroll
    for (int o=0;o<16;o++){
      float t1 = wvv*linv[(64+j)*16+o];
      float t2 = wcx*linv[(80+j)*16+o];
      acc[o][0] = fmaf(t1, wx, fmaf(t2, cx, acc[o][0]));
      acc[o][1] = fmaf(t1, wy, fmaf(t2, cy, acc[o][1]));
      acc[o][2] = fmaf(t1, wz, fmaf(t2, cz, acc[o][2]));
    }
  }
  #pragma unroll
  for (int o=0;o<16;o++){
    atomicAdd(agg_v + (size_t)dst*48 + o*3+0, DEGN*acc[o][0]);
    atomicAdd(agg_v + (size_t)dst*48 + o*3+1, DEGN*acc[o][1]);
    atomicAdd(agg_v + (size_t)dst*48 + o*3+2, DEGN*acc[o][2]);
  }
}

// ---- node update: out_s = agg_s@lin_s ; s += silu(out_s); v += agg_v*sigmoid(out_s@gate_w) ----
__global__ __launch_bounds__(256) void node_update(
    const float* __restrict__ agg_s, const float* __restrict__ agg_v,
    const float* __restrict__ lin_s, const float* __restrict__ gate_w,
    float* __restrict__ s, float* __restrict__ v)
{
  int n = blockIdx.x*256 + threadIdx.x;
  if (n >= N_NODES) return;
  float outs[64];
  #pragma unroll
  for (int o=0;o<64;o++) outs[o]=0.f;
  for (int i=0;i<80;i+=4){
    float4 a4 = *(const float4*)(agg_s + (size_t)n*80 + i);
    float av[4]={a4.x,a4.y,a4.z,a4.w};
    #pragma unroll
    for (int q=0;q<4;q++){
      float a = av[q];
      #pragma unroll
      for (int o=0;o<64;o++) outs[o] = fmaf(a, lin_s[(i+q)*64+o], outs[o]);
    }
  }
  float g[16];
  #pragma unroll
  for (int j=0;j<16;j++) g[j]=0.f;
  for (int o=0;o<64;o++){
    float x = outs[o];
    #pragma unroll
    for (int j=0;j<16;j++) g[j] = fmaf(x, gate_w[o*16+j], g[j]);
    s[(size_t)n*64+o] += fsilu(x);
  }
  #pragma unroll
  for (int j=0;j<16;j++){
    float gv = fsig(g[j]);
    v[(size_t)n*48+j*3+0] += agg_v[(size_t)n*48+j*3+0]*gv;
    v[(size_t)n*48+j*3+1] += agg_v[(size_t)n*48+j*3+1]*gv;
    v[(size_t)n*48+j*3+2] += agg_v[(size_t)n*48+j*3+2]*gv;
  }
}

// ---- output head ----
__global__ __launch_bounds__(256) void head_kernel(
    const float* __restrict__ s, const float* __restrict__ v,
    const float* __restrict__ hs1, const float* __restrict__ hg,
    const float* __restrict__ hs2, const float* __restrict__ hv2,
    float* __restrict__ out)
{
  int n = blockIdx.x*256 + threadIdx.x;
  if (n >= N_NODES) return;
  float sv[64];
  const float4* sp = (const float4*)(s + (size_t)n*64);
  #pragma unroll
  for (int q=0;q<16;q++){ float4 t=sp[q]; sv[4*q]=t.x; sv[4*q+1]=t.y; sv[4*q+2]=t.z; sv[4*q+3]=t.w; }
  float h[64];
  #pragma unroll
  for (int o=0;o<64;o++) h[o]=0.f;
  for (int k=0;k<64;k++){
    float x = sv[k];
    #pragma unroll
    for (int o=0;o<64;o++) h[o] = fmaf(x, hs1[k*64+o], h[o]);
  }
  #pragma unroll
  for (int o=0;o<64;o++) h[o] = fsilu(h[o]);
  float g[16];
  #pragma unroll
  for (int j=0;j<16;j++) g[j]=0.f;
  float ps = 0.f;
  for (int o=0;o<64;o++){
    float x = h[o];
    #pragma unroll
    for (int j=0;j<16;j++) g[j] = fmaf(x, hg[o*16+j], g[j]);
    ps = fmaf(x, hs2[o], ps);
  }
  float pvx=0.f, pvy=0.f, pvz=0.f;
  #pragma unroll
  for (int j=0;j<16;j++){
    float gv = fsig(g[j]) * hv2[j];
    pvx = fmaf(v[(size_t)n*48+j*3+0], gv, pvx);
    pvy = fmaf(v[(size_t)n*48+j*3+1], gv, pvy);
    pvz = fmaf(v[(size_t)n*48+j*3+2], gv, pvz);
  }
  *(float4*)(out + (size_t)n*4) = make_float4(ps, pvx, pvy, pvz);
}

extern "C" void kernel_launch(void* const* d_in, const int* in_sizes, int n_in,
                              void* d_out, int out_size, void* d_ws, size_t ws_size,
                              hipStream_t stream)
{
  const float* pos       = (const float*)d_in[0];
  const int*   ei        = (const int*)  d_in[1];
  const int*   bond_mask = (const int*)  d_in[2];
  const int*   atom_type = (const int*)  d_in[3];
  const float* atom_emb  = (const float*)d_in[4];
  const float* bond_emb  = (const float*)d_in[5];
  const float* w_init    = (const float*)d_in[6];
  const float* mlp_w1    = (const float*)d_in[7];
  const float* mlp_b1    = (const float*)d_in[8];
  const float* mlp_w2    = (const float*)d_in[9];
  const float* lin_s     = (const float*)d_in[10];
  const float* lin_v     = (const float*)d_in[11];
  const float* gate_w    = (const float*)d_in[12];
  const float* hs1       = (const float*)d_in[13];
  const float* hg        = (const float*)d_in[14];
  const float* hs2       = (const float*)d_in[15];
  const float* hv2       = (const float*)d_in[16];
  float* out = (float*)d_out;

  char* ws = (char*)d_ws;
  size_t off = 0;
  auto alloc = [&](size_t nfloats){ float* p = (float*)(ws + off); off += nfloats*sizeof(float); return p; };
  float* ea   = alloc((size_t)N_EDGES*16);
  float* y1   = alloc((size_t)N_EDGES*3);
  float* sbuf = alloc((size_t)N_NODES*64);
  float* vbuf = alloc((size_t)N_NODES*48);
  float* aggs = alloc((size_t)N_NODES*80);   // aggs+aggv contiguous -> single memset
  float* aggv = alloc((size_t)N_NODES*48);
  float* w2t  = alloc((size_t)3*176*64);

  dim3 blk(256);
  int gE = (N_EDGES + 255)/256;
  int gN = (N_NODES + 255)/256;

  hipMemsetAsync(vbuf, 0, (size_t)N_NODES*48*sizeof(float), stream);
  prep_edges<<<gE, blk, 0, stream>>>(pos, ei, bond_mask, bond_emb, ea, y1);
  init_nodes<<<gN, blk, 0, stream>>>(atom_type, atom_emb, w_init, sbuf);
  transpose_w2<<<(3*64*176 + 255)/256, blk, 0, stream>>>(mlp_w2, w2t);

  for (int l=0;l<3;l++){
    hipMemsetAsync(aggs, 0, (size_t)N_NODES*(80+48)*sizeof(float), stream);
    edge_msg<<<gE, blk, 0, stream>>>(ea, y1, ei, sbuf, vbuf,
        mlp_w1 + (size_t)l*16*64, mlp_b1 + (size_t)l*64,
        w2t + (size_t)l*176*64, lin_v + (size_t)l*96*16,
        aggs, aggv);
    node_update<<<gN, blk, 0, stream>>>(aggs, aggv,
        lin_s + (size_t)l*80*64, gate_w + (size_t)l*64*16, sbuf, vbuf);
  }
  head_kernel<<<gN, blk, 0, stream>>>(sbuf, vbuf, hs1, hg, hs2, hv2, out);
}

// Round 2
// 2424.109 us; speedup vs baseline: 4.0238x; 4.0238x over previous
//
#include <hip/hip_runtime.h>
#include <math.h>

#define N_NODES 30000
#define N_EDGES 480000
#define DEGN 0.25f   // 1/sqrt(16)

__device__ __forceinline__ float fsilu(float x){ return x / (1.f + __expf(-x)); }
__device__ __forceinline__ float fsig (float x){ return 1.f / (1.f + __expf(-x)); }

__device__ __forceinline__ unsigned bf16rn(float x){
  unsigned u = __float_as_uint(x);
  return (u + 0x7fffu + ((u>>16)&1u)) >> 16;
}
__device__ __forceinline__ unsigned pack2(float a, float b){
  return bf16rn(a) | (bf16rn(b)<<16);
}
__device__ __forceinline__ float bflo(unsigned u){ return __uint_as_float(u<<16); }
__device__ __forceinline__ float bfhi(unsigned u){ return __uint_as_float(u & 0xffff0000u); }

// ---- per-edge geometry + edge_attr (once) ----
__global__ __launch_bounds__(256) void prep_edges(
    const float* __restrict__ pos, const int* __restrict__ ei,
    const int* __restrict__ bond_mask, const float* __restrict__ bond_emb,
    float* __restrict__ ea, float* __restrict__ y1)
{
  int e = blockIdx.x*256 + threadIdx.x;
  if (e >= N_EDGES) return;
  int src = ei[e], dst = ei[N_EDGES + e];
  float ax = pos[src*3+0], ay = pos[src*3+1], az = pos[src*3+2];
  float bx = pos[dst*3+0], by = pos[dst*3+1], bz = pos[dst*3+2];
  float vx = ax-bx, vy = ay-by, vz = az-bz;
  float r = sqrtf(vx*vx + vy*vy + vz*vz);
  float inv = 1.f / fmaxf(r, 1e-9f);
  const float s3 = 1.7320508075688772f;
  y1[e*3+0] = s3*vx*inv; y1[e*3+1] = s3*vy*inv; y1[e*3+2] = s3*vz*inv;
  int bm = bond_mask[e];
  float eav[16];
  #pragma unroll
  for (int q=0;q<8;q++) eav[q] = bond_emb[bm*8+q];
  const float step = 5.0f/9.0f;
  #pragma unroll
  for (int j=0;j<8;j++){
    float vj = (float)(j+1)*step;
    float d = (r - vj)/step;
    eav[8+j] = __expf(-d*d) * (1.0f/1.12f);
  }
  float4* o = (float4*)(ea + (size_t)e*16);
  o[0] = make_float4(eav[0],eav[1],eav[2],eav[3]);
  o[1] = make_float4(eav[4],eav[5],eav[6],eav[7]);
  o[2] = make_float4(eav[8],eav[9],eav[10],eav[11]);
  o[3] = make_float4(eav[12],eav[13],eav[14],eav[15]);
}

// ---- CSR build ----
__global__ __launch_bounds__(256) void count_deg(const int* __restrict__ ei, int* __restrict__ deg)
{
  int e = blockIdx.x*256 + threadIdx.x;
  if (e >= N_EDGES) return;
  atomicAdd(deg + ei[N_EDGES + e], 1);
}

__global__ __launch_bounds__(1024) void scan_deg(const int* __restrict__ deg,
                                                 int* __restrict__ off, int* __restrict__ cur)
{
  __shared__ int part[1024];
  int t = threadIdx.x;
  int base = t*30;
  int local[30];
  int s = 0;
  #pragma unroll
  for (int i=0;i<30;i++){
    int idx = base + i;
    int d = (idx < N_NODES) ? deg[idx] : 0;
    local[i] = s; s += d;
  }
  part[t] = s; __syncthreads();
  for (int stp=1; stp<1024; stp<<=1){
    int v = (t >= stp) ? part[t-stp] : 0;
    __syncthreads();
    part[t] += v;
    __syncthreads();
  }
  int prefix = (t==0) ? 0 : part[t-1];
  #pragma unroll
  for (int i=0;i<30;i++){
    int idx = base + i;
    if (idx < N_NODES){ int o = prefix + local[i]; off[idx] = o; cur[idx] = o; }
  }
  if (t == 1023) off[N_NODES] = part[1023];
}

__global__ __launch_bounds__(256) void scatter_edges(const int* __restrict__ ei,
                                                     int* __restrict__ cur, int* __restrict__ csr)
{
  int e = blockIdx.x*256 + threadIdx.x;
  if (e >= N_EDGES) return;
  int p = atomicAdd(cur + ei[N_EDGES + e], 1);
  csr[p] = e;
}

// ---- s = atom_emb[atom_type] @ w_init ----
__global__ __launch_bounds__(256) void init_nodes(
    const int* __restrict__ atom_type, const float* __restrict__ atom_emb,
    const float* __restrict__ w_init, float* __restrict__ s)
{
  int n = blockIdx.x*256 + threadIdx.x;
  if (n >= N_NODES) return;
  int t = atom_type[n];
  float acc[64];
  #pragma unroll
  for (int o=0;o<64;o++) acc[o]=0.f;
  for (int k=0;k<64;k++){
    float ek = atom_emb[t*64+k];
    #pragma unroll
    for (int o=0;o<64;o++) acc[o] = fmaf(ek, w_init[k*64+o], acc[o]);
  }
  float4* so = (float4*)(s + (size_t)n*64);
  #pragma unroll
  for (int q=0;q<16;q++) so[q] = make_float4(acc[4*q],acc[4*q+1],acc[4*q+2],acc[4*q+3]);
}

// ---- W2 [3][64][176] -> W2T [3][176][64] ----
__global__ void transpose_w2(const float* __restrict__ w2, float* __restrict__ w2t)
{
  int i = blockIdx.x*256 + threadIdx.x;
  if (i >= 3*64*176) return;
  int l = i / (64*176); int rem = i - l*(64*176);
  int k = rem / 176, c = rem - k*176;
  w2t[l*176*64 + c*64 + k] = w2[i];
}

// ---- fused edge kernel: MLP -> TP messages (lin_v folded) -> bf16 row store ----
// msg row layout (128 bf16): [0..64)=w_ss*se ; [64..80)=w_vs*(v.y1) ; [80+o*3+c)=folded vec
__global__ __launch_bounds__(256) void edge_msg2(
    const float* __restrict__ ea, const float* __restrict__ y1v,
    const int* __restrict__ ei,
    const float* __restrict__ s, const float* __restrict__ v,
    const float* __restrict__ W1,    // [16][64]
    const float* __restrict__ b1,    // [64]
    const float* __restrict__ W2T,   // [176][64]
    const float* __restrict__ linv,  // [96][16]
    unsigned* __restrict__ msg)      // [E][64] u32 (=128 bf16)
{
  int e = blockIdx.x*256 + threadIdx.x;
  if (e >= N_EDGES) return;
  int src = ei[e];

  // h = silu(ea @ W1 + b1)
  float h[64];
  {
    float eav[16];
    const float4* eap = (const float4*)(ea + (size_t)e*16);
    #pragma unroll
    for (int q=0;q<4;q++){ float4 t4 = eap[q]; eav[4*q]=t4.x; eav[4*q+1]=t4.y; eav[4*q+2]=t4.z; eav[4*q+3]=t4.w; }
    #pragma unroll
    for (int k=0;k<64;k++) h[k] = b1[k];
    #pragma unroll
    for (int j=0;j<16;j++){
      float a = eav[j];
      #pragma unroll
      for (int k=0;k<64;k++) h[k] = fmaf(a, W1[j*64+k], h[k]);
    }
    #pragma unroll
    for (int k=0;k<64;k++) h[k] = fsilu(h[k]);
  }

  float yx = y1v[e*3+0], yy = y1v[e*3+1], yz = y1v[e*3+2];
  unsigned* m32 = msg + (size_t)e*64;

  // phase B: scalar channels (w_ss*se) and a_o = sum_i w_sv_i*se_i*lin_v[i][o]
  float a_o[16];
  #pragma unroll
  for (int o=0;o<16;o++) a_o[o]=0.f;

  for (int i0=0;i0<64;i0+=4){
    float4 se4 = *(const float4*)(s + (size_t)src*64 + i0);
    float se[4] = {se4.x, se4.y, se4.z, se4.w};
    float wss[4] = {0,0,0,0}, wsv[4] = {0,0,0,0};
    #pragma unroll
    for (int k=0;k<64;k++){
      float hk = h[k];
      #pragma unroll
      for (int q=0;q<4;q++){
        wss[q] = fmaf(hk, W2T[(i0+q)*64+k], wss[q]);
        wsv[q] = fmaf(hk, W2T[(80+i0+q)*64+k], wsv[q]);
      }
    }
    unsigned u0 = pack2(DEGN*wss[0]*se[0], DEGN*wss[1]*se[1]);
    unsigned u1 = pack2(DEGN*wss[2]*se[2], DEGN*wss[3]*se[3]);
    *(uint2*)(m32 + (i0>>1)) = make_uint2(u0, u1);
    #pragma unroll
    for (int q=0;q<4;q++){
      float t = wsv[q]*se[q];
      #pragma unroll
      for (int o=0;o<16;o++) a_o[o] = fmaf(t, linv[(i0+q)*16+o], a_o[o]);
    }
  }

  // phase C: vector channels; accv[o*3+c] accumulates (m_v @ lin_v), DEGN applied at pack
  float accv[48];
  #pragma unroll
  for (int o=0;o<16;o++){ accv[o*3+0]=a_o[o]*yx; accv[o*3+1]=a_o[o]*yy; accv[o*3+2]=a_o[o]*yz; }

  float dv[16];
  for (int j=0;j<16;j++){
    float wx = v[(size_t)src*48 + j*3 + 0];
    float wy = v[(size_t)src*48 + j*3 + 1];
    float wz = v[(size_t)src*48 + j*3 + 2];
    float wvs=0.f, wvv=0.f, wcx=0.f;
    #pragma unroll
    for (int k=0;k<64;k++){
      float hk = h[k];
      wvs = fmaf(hk, W2T[( 64+j)*64+k], wvs);
      wvv = fmaf(hk, W2T[(144+j)*64+k], wvv);
      wcx = fmaf(hk, W2T[(160+j)*64+k], wcx);
    }
    dv[j] = DEGN * wvs * (wx*yx + wy*yy + wz*yz);
    float cx = wy*yz - wz*yy;
    float cy = wz*yx - wx*yz;
    float cz = wx*yy - wy*yx;
    #pragma unroll
    for (int o=0;o<16;o++){
      float t1 = wvv*linv[(64+j)*16+o];
      float t2 = wcx*linv[(80+j)*16+o];
      accv[o*3+0] = fmaf(t1, wx, fmaf(t2, cx, accv[o*3+0]));
      accv[o*3+1] = fmaf(t1, wy, fmaf(t2, cy, accv[o*3+1]));
      accv[o*3+2] = fmaf(t1, wz, fmaf(t2, cz, accv[o*3+2]));
    }
  }

  // dv -> m32[32..40)
  {
    uint4 p0, p1;
    p0.x = pack2(dv[0],dv[1]);  p0.y = pack2(dv[2],dv[3]);
    p0.z = pack2(dv[4],dv[5]);  p0.w = pack2(dv[6],dv[7]);
    p1.x = pack2(dv[8],dv[9]);  p1.y = pack2(dv[10],dv[11]);
    p1.z = pack2(dv[12],dv[13]);p1.w = pack2(dv[14],dv[15]);
    *(uint4*)(m32 + 32) = p0;
    *(uint4*)(m32 + 36) = p1;
  }
  // accv (×DEGN) -> m32[40..64)
  #pragma unroll
  for (int b=0;b<6;b++){
    uint4 p;
    p.x = pack2(DEGN*accv[8*b+0], DEGN*accv[8*b+1]);
    p.y = pack2(DEGN*accv[8*b+2], DEGN*accv[8*b+3]);
    p.z = pack2(DEGN*accv[8*b+4], DEGN*accv[8*b+5]);
    p.w = pack2(DEGN*accv[8*b+6], DEGN*accv[8*b+7]);
    *(uint4*)(m32 + 40 + 4*b) = p;
  }
}

// ---- CSR gather: 16 lanes per node, 8 channels per lane ----
__global__ __launch_bounds__(256) void gather_nodes(
    const unsigned* __restrict__ msg,   // [E][64] u32
    const int* __restrict__ off, const int* __restrict__ csr,
    float* __restrict__ agg)            // [N][128] f32
{
  int tid = threadIdx.x;
  int n = blockIdx.x*16 + (tid >> 4);
  int l = tid & 15;
  if (n >= N_NODES) return;
  float acc[8];
  #pragma unroll
  for (int q=0;q<8;q++) acc[q]=0.f;
  int k1 = off[n+1];
  for (int k=off[n]; k<k1; k++){
    int e = csr[k];
    uint4 m = *(const uint4*)(msg + (size_t)e*64 + l*4);
    acc[0] += bflo(m.x); acc[1] += bfhi(m.x);
    acc[2] += bflo(m.y); acc[3] += bfhi(m.y);
    acc[4] += bflo(m.z); acc[5] += bfhi(m.z);
    acc[6] += bflo(m.w); acc[7] += bfhi(m.w);
  }
  float4* o = (float4*)(agg + (size_t)n*128 + l*8);
  o[0] = make_float4(acc[0],acc[1],acc[2],acc[3]);
  o[1] = make_float4(acc[4],acc[5],acc[6],acc[7]);
}

// ---- node update: out_s = agg_s@lin_s ; s += silu(out_s); v += agg_v*sigmoid(out_s@gate_w) ----
__global__ __launch_bounds__(256) void node_update(
    const float* __restrict__ agg,      // [N][128]
    const float* __restrict__ lin_s, const float* __restrict__ gate_w,
    float* __restrict__ s, float* __restrict__ v)
{
  int n = blockIdx.x*256 + threadIdx.x;
  if (n >= N_NODES) return;
  const float* row = agg + (size_t)n*128;
  float outs[64];
  #pragma unroll
  for (int o=0;o<64;o++) outs[o]=0.f;
  for (int i=0;i<80;i+=4){
    float4 a4 = *(const float4*)(row + i);
    float av[4]={a4.x,a4.y,a4.z,a4.w};
    #pragma unroll
    for (int q=0;q<4;q++){
      float a = av[q];
      #pragma unroll
      for (int o=0;o<64;o++) outs[o] = fmaf(a, lin_s[(i+q)*64+o], outs[o]);
    }
  }
  float g[16];
  #pragma unroll
  for (int j=0;j<16;j++) g[j]=0.f;
  for (int o=0;o<64;o++){
    float x = outs[o];
    #pragma unroll
    for (int j=0;j<16;j++) g[j] = fmaf(x, gate_w[o*16+j], g[j]);
    s[(size_t)n*64+o] += fsilu(x);
  }
  #pragma unroll
  for (int j=0;j<16;j++){
    float gv = fsig(g[j]);
    v[(size_t)n*48+j*3+0] += row[80+j*3+0]*gv;
    v[(size_t)n*48+j*3+1] += row[80+j*3+1]*gv;
    v[(size_t)n*48+j*3+2] += row[80+j*3+2]*gv;
  }
}

// ---- output head ----
__global__ __launch_bounds__(256) void head_kernel(
    const float* __restrict__ s, const float* __restrict__ v,
    const float* __restrict__ hs1, const float* __restrict__ hg,
    const float* __restrict__ hs2, const float* __restrict__ hv2,
    float* __restrict__ out)
{
  int n = blockIdx.x*256 + threadIdx.x;
  if (n >= N_NODES) return;
  float sv[64];
  const float4* sp = (const float4*)(s + (size_t)n*64);
  #pragma unroll
  for (int q=0;q<16;q++){ float4 t=sp[q]; sv[4*q]=t.x; sv[4*q+1]=t.y; sv[4*q+2]=t.z; sv[4*q+3]=t.w; }
  float h[64];
  #pragma unroll
  for (int o=0;o<64;o++) h[o]=0.f;
  for (int k=0;k<64;k++){
    float x = sv[k];
    #pragma unroll
    for (int o=0;o<64;o++) h[o] = fmaf(x, hs1[k*64+o], h[o]);
  }
  #pragma unroll
  for (int o=0;o<64;o++) h[o] = fsilu(h[o]);
  float g[16];
  #pragma unroll
  for (int j=0;j<16;j++) g[j]=0.f;
  float ps = 0.f;
  for (int o=0;o<64;o++){
    float x = h[o];
    #pragma unroll
    for (int j=0;j<16;j++) g[j] = fmaf(x, hg[o*16+j], g[j]);
    ps = fmaf(x, hs2[o], ps);
  }
  float pvx=0.f, pvy=0.f, pvz=0.f;
  #pragma unroll
  for (int j=0;j<16;j++){
    float gv = fsig(g[j]) * hv2[j];
    pvx = fmaf(v[(size_t)n*48+j*3+0], gv, pvx);
    pvy = fmaf(v[(size_t)n*48+j*3+1], gv, pvy);
    pvz = fmaf(v[(size_t)n*48+j*3+2], gv, pvz);
  }
  *(float4*)(out + (size_t)n*4) = make_float4(ps, pvx, pvy, pvz);
}

extern "C" void kernel_launch(void* const* d_in, const int* in_sizes, int n_in,
                              void* d_out, int out_size, void* d_ws, size_t ws_size,
                              hipStream_t stream)
{
  const float* pos       = (const float*)d_in[0];
  const int*   ei        = (const int*)  d_in[1];
  const int*   bond_mask = (const int*)  d_in[2];
  const int*   atom_type = (const int*)  d_in[3];
  const float* atom_emb  = (const float*)d_in[4];
  const float* bond_emb  = (const float*)d_in[5];
  const float* w_init    = (const float*)d_in[6];
  const float* mlp_w1    = (const float*)d_in[7];
  const float* mlp_b1    = (const float*)d_in[8];
  const float* mlp_w2    = (const float*)d_in[9];
  const float* lin_s     = (const float*)d_in[10];
  const float* lin_v     = (const float*)d_in[11];
  const float* gate_w    = (const float*)d_in[12];
  const float* hs1       = (const float*)d_in[13];
  const float* hg        = (const float*)d_in[14];
  const float* hs2       = (const float*)d_in[15];
  const float* hv2       = (const float*)d_in[16];
  float* out = (float*)d_out;

  char* ws = (char*)d_ws;
  size_t off_b = 0;
  auto alloc = [&](size_t nelem, size_t esz){ void* p = (void*)(ws + off_b); off_b += ((nelem*esz + 15)/16)*16; return p; };
  float*    ea   = (float*)   alloc((size_t)N_EDGES*16, 4);
  float*    y1   = (float*)   alloc((size_t)N_EDGES*3, 4);
  float*    sbuf = (float*)   alloc((size_t)N_NODES*64, 4);
  float*    vbuf = (float*)   alloc((size_t)N_NODES*48, 4);
  float*    agg  = (float*)   alloc((size_t)N_NODES*128, 4);
  float*    w2t  = (float*)   alloc((size_t)3*176*64, 4);
  unsigned* msg  = (unsigned*)alloc((size_t)N_EDGES*64, 4);   // 128 bf16 per edge
  int*      deg  = (int*)     alloc(N_NODES, 4);
  int*      offs = (int*)     alloc(N_NODES+1, 4);
  int*      cur  = (int*)     alloc(N_NODES, 4);
  int*      csr  = (int*)     alloc(N_EDGES, 4);

  dim3 blk(256);
  int gE = (N_EDGES + 255)/256;
  int gN = (N_NODES + 255)/256;
  int gG = (N_NODES + 15)/16;

  hipMemsetAsync(vbuf, 0, (size_t)N_NODES*48*sizeof(float), stream);
  hipMemsetAsync(deg, 0, (size_t)N_NODES*sizeof(int), stream);

  count_deg<<<gE, blk, 0, stream>>>(ei, deg);
  scan_deg<<<1, 1024, 0, stream>>>(deg, offs, cur);
  scatter_edges<<<gE, blk, 0, stream>>>(ei, cur, csr);

  prep_edges<<<gE, blk, 0, stream>>>(pos, ei, bond_mask, bond_emb, ea, y1);
  init_nodes<<<gN, blk, 0, stream>>>(atom_type, atom_emb, w_init, sbuf);
  transpose_w2<<<(3*64*176 + 255)/256, blk, 0, stream>>>(mlp_w2, w2t);

  for (int l=0;l<3;l++){
    edge_msg2<<<gE, blk, 0, stream>>>(ea, y1, ei, sbuf, vbuf,
        mlp_w1 + (size_t)l*16*64, mlp_b1 + (size_t)l*64,
        w2t + (size_t)l*176*64, lin_v + (size_t)l*96*16,
        msg);
    gather_nodes<<<gG, blk, 0, stream>>>(msg, offs, csr, agg);
    node_update<<<gN, blk, 0, stream>>>(agg,
        lin_s + (size_t)l*80*64, gate_w + (size_t)l*64*16, sbuf, vbuf);
  }
  head_kernel<<<gN, blk, 0, stream>>>(sbuf, vbuf, hs1, hg, hs2, hv2, out);
}